// Round 2
// baseline (566.016 us; speedup 1.0000x reference)
//
#include <hip/hip_runtime.h>

#define HID 2048
#define NTHREADS 256

// One block per token t in [0, T).  Layouts (fp32):
//   hs  [4, T, HID], act [T, HID], rns [HID], rw [HID,4],
//   pw  [4,16], cw [4,4], cscale [HID], out [4, T, HID]
__global__ __launch_bounds__(NTHREADS) void altup_fused(
    const float* __restrict__ hs,
    const float* __restrict__ act,
    const float* __restrict__ rns,
    const float* __restrict__ rw,
    const float* __restrict__ pw,
    const float* __restrict__ cw,
    const float* __restrict__ cscale,
    float* __restrict__ out,
    int T)
{
    const int t   = blockIdx.x;
    const int tid = threadIdx.x;
    const int h0  = tid * 8;                 // each thread owns 8 contiguous h

    __shared__ float s_red[4][10];
    __shared__ float s_raw[16];
    __shared__ float s_coef[4];

    const size_t tok = (size_t)t * HID;
    const size_t strideN = (size_t)T * HID;

    // ---- phase 1: reductions over H (hs[0] and activated) ----
    float x0v[8], av[8], nsv[8], wl[32];
    *(float4*)(x0v + 0) = *(const float4*)(hs  + tok + h0 + 0);
    *(float4*)(x0v + 4) = *(const float4*)(hs  + tok + h0 + 4);
    *(float4*)(av  + 0) = *(const float4*)(act + tok + h0 + 0);
    *(float4*)(av  + 4) = *(const float4*)(act + tok + h0 + 4);
    *(float4*)(nsv + 0) = *(const float4*)(rns + h0 + 0);
    *(float4*)(nsv + 4) = *(const float4*)(rns + h0 + 4);
    #pragma unroll
    for (int q = 0; q < 8; ++q)
        *(float4*)(wl + q * 4) = *(const float4*)(rw + (size_t)h0 * 4 + q * 4);

    float r[10];
    #pragma unroll
    for (int k = 0; k < 10; ++k) r[k] = 0.f;
    #pragma unroll
    for (int j = 0; j < 8; ++j) {
        float x0 = x0v[j];
        float a  = av[j];
        float ns = nsv[j];
        r[0] += x0 * x0;          // sum sq hs0
        r[1] += a * a;            // sum sq act
        float xs = x0 * ns, as_ = a * ns;
        #pragma unroll
        for (int n = 0; n < 4; ++n) {
            float w = wl[j * 4 + n];
            r[2 + n] += xs  * w;  // router dot, hs0 path
            r[6 + n] += as_ * w;  // router dot, act path
        }
    }

    // wave(64)-level butterfly, then cross-wave via LDS
    #pragma unroll
    for (int off = 32; off > 0; off >>= 1) {
        #pragma unroll
        for (int k = 0; k < 10; ++k) r[k] += __shfl_down(r[k], off, 64);
    }
    const int wave = tid >> 6, lane = tid & 63;
    if (lane == 0) {
        #pragma unroll
        for (int k = 0; k < 10; ++k) s_red[wave][k] = r[k];
    }
    __syncthreads();

    if (tid == 0) {
        float acc[10];
        #pragma unroll
        for (int k = 0; k < 10; ++k)
            acc[k] = s_red[0][k] + s_red[1][k] + s_red[2][k] + s_red[3][k];
        const float invH = 1.0f / (float)HID;
        float inv_p = rsqrtf(acc[0] * invH + 1e-6f);
        float inv_c = rsqrtf(acc[1] * invH + 1e-6f);
        float mp[4], mc[4];
        #pragma unroll
        for (int n = 0; n < 4; ++n) {
            mp[n] = tanhf(acc[2 + n] * inv_p * invH);
            mc[n] = tanhf(acc[6 + n] * inv_c * invH);
        }
        // raw[m*4+n] = sum_k mp[k] * pred_w[k, m*4+n]
        #pragma unroll
        for (int kk = 0; kk < 16; ++kk) {
            float s = 0.f;
            #pragma unroll
            for (int k = 0; k < 4; ++k) s += mp[k] * pw[k * 16 + kk];
            s_raw[kk] = s;
        }
        // coef[m] = 1 + sum_k mc[k] * corr_w[k, m]
        #pragma unroll
        for (int m = 0; m < 4; ++m) {
            float s = 1.0f;
            #pragma unroll
            for (int k = 0; k < 4; ++k) s += mc[k] * cw[k * 4 + m];
            s_coef[m] = s;
        }
    }
    __syncthreads();

    float raw[16], coef[4];
    #pragma unroll
    for (int k = 0; k < 16; ++k) raw[k] = s_raw[k];
    #pragma unroll
    for (int m = 0; m < 4; ++m) coef[m] = s_coef[m];

    // ---- phase 2: elementwise over the 8 owned h positions ----
    float x1v[8], x2v[8], x3v[8], csv[8];
    *(float4*)(x1v + 0) = *(const float4*)(hs + 1 * strideN + tok + h0 + 0);
    *(float4*)(x1v + 4) = *(const float4*)(hs + 1 * strideN + tok + h0 + 4);
    *(float4*)(x2v + 0) = *(const float4*)(hs + 2 * strideN + tok + h0 + 0);
    *(float4*)(x2v + 4) = *(const float4*)(hs + 2 * strideN + tok + h0 + 4);
    *(float4*)(x3v + 0) = *(const float4*)(hs + 3 * strideN + tok + h0 + 0);
    *(float4*)(x3v + 4) = *(const float4*)(hs + 3 * strideN + tok + h0 + 4);
    *(float4*)(csv + 0) = *(const float4*)(cscale + h0 + 0);
    *(float4*)(csv + 4) = *(const float4*)(cscale + h0 + 4);

    float o[4][8];
    #pragma unroll
    for (int j = 0; j < 8; ++j) {
        float x[4] = { x0v[j], x1v[j], x2v[j], x3v[j] };
        float a  = av[j];
        float cs = csv[j];
        float pred[4];
        #pragma unroll
        for (int m = 0; m < 4; ++m)
            pred[m] = x[0] * raw[m * 4 + 0] + x[1] * raw[m * 4 + 1]
                    + x[2] * raw[m * 4 + 2] + x[3] * raw[m * 4 + 3] + x[m];
        float innov = a - pred[0];
        #pragma unroll
        for (int m = 0; m < 4; ++m)
            o[m][j] = (pred[m] + innov * coef[m]) * cs;
    }
    #pragma unroll
    for (int m = 0; m < 4; ++m) {
        *(float4*)(out + m * strideN + tok + h0 + 0) = *(const float4*)(o[m] + 0);
        *(float4*)(out + m * strideN + tok + h0 + 4) = *(const float4*)(o[m] + 4);
    }
}

extern "C" void kernel_launch(void* const* d_in, const int* in_sizes, int n_in,
                              void* d_out, int out_size, void* d_ws, size_t ws_size,
                              hipStream_t stream) {
    const float* hs  = (const float*)d_in[0]; // [4,B,S,H]
    const float* act = (const float*)d_in[1]; // [B,S,H]
    const float* rns = (const float*)d_in[2]; // [H]
    const float* rw  = (const float*)d_in[3]; // [H,4]
    const float* pw  = (const float*)d_in[4]; // [4,16]
    const float* cw  = (const float*)d_in[5]; // [4,4]
    const float* cs  = (const float*)d_in[6]; // [H]
    float* out = (float*)d_out;               // [4,B,S,H]

    const int T = in_sizes[1] / HID;  // B*S tokens
    altup_fused<<<dim3(T), dim3(NTHREADS), 0, stream>>>(hs, act, rns, rw, pw, cw, cs, out, T);
}